// Round 5
// baseline (195.840 us; speedup 1.0000x reference)
//
#include <hip/hip_runtime.h>
#include <hip/hip_bf16.h>
#include <math.h>

// Problem: IntraSampleNTXEntLoss  S=4, V=2, B=8192, D=512, T=0.1
// views: (S,V,B,D) fp32, flat index ((s*V+v)*B + b)*D + d
// Output: scalar mean loss.
//
// R4: R3 minus nontemporal. The harness restores d_in (134 MiB < 256 MiB L3)
// right before each timed replay, so the input is L3-resident; nt loads hint
// the caches away from serving/retaining it. Plain global_load_dwordx4 lets
// L3 serve the single pass (~2-3x HBM read BW). Keep: one wave per b, all 16
// loads issued up front (MLP), 30 unique dots (even-even Gram symmetric),
// DPP-only wave reduction, lane 63 computes 4 anchor losses (7 finite logits
// each; masked -inf never materialized), one partial per wave, no LDS in the
// main kernel. Reduce kernel widened to 1024 threads (8 L2-hot loads/thread).

#define NS 4
#define NB 8192
#define ND 512
#define T_INV 10.0f
#define WAVES_PER_BLOCK 4
#define NBLOCKS (NB / WAVES_PER_BLOCK)
#define NPART NB  // one partial per wave (= per batch element)

typedef float fx4 __attribute__((ext_vector_type(4)));

__device__ __forceinline__ float dot8(const fx4& a0, const fx4& a1,
                                      const fx4& b0, const fx4& b1) {
    return a0.x*b0.x + a0.y*b0.y + a0.z*b0.z + a0.w*b0.w +
           a1.x*b1.x + a1.y*b1.y + a1.z*b1.z + a1.w*b1.w;
}

template <int CTRL, int RM>
__device__ __forceinline__ float dpp_add(float v, float x) {
    int xi = __builtin_bit_cast(int, x);
    int ri = __builtin_amdgcn_update_dpp(0, xi, CTRL, RM, 0xf, true);
    return v + __builtin_bit_cast(float, ri);
}

// Full 64-lane sum; result valid in lane 63. All DPP (VALU pipe only).
__device__ __forceinline__ float wave_sum63(float v) {
    v = dpp_add<0x111, 0xf>(v, v);  // row_shr:1
    v = dpp_add<0x112, 0xf>(v, v);  // row_shr:2
    v = dpp_add<0x114, 0xf>(v, v);  // row_shr:4
    v = dpp_add<0x118, 0xf>(v, v);  // row_shr:8  -> lane 15 of each row16
    v = dpp_add<0x142, 0xa>(v, v);  // row_bcast:15 into rows 1,3
    v = dpp_add<0x143, 0xc>(v, v);  // row_bcast:31 into rows 2,3 -> lane 63
    return v;
}

__global__ __launch_bounds__(256) void ntxent_main(const float* __restrict__ views,
                                                   float* __restrict__ partial) {
    const int wave = threadIdx.x >> 6;
    const int lane = threadIdx.x & 63;
    const int b = blockIdx.x * WAVES_PER_BLOCK + wave;
    const int off = 4 * lane;  // first float4; second at +256 floats

    // Phase 1: issue ALL 16 loads (8 rows x 2 float4); 16 in flight.
    // Plain loads (no nt) so the freshly-restored, L3-resident input is
    // served from Infinity Cache.
    fx4 V[8][2];
#pragma unroll
    for (int k = 0; k < 8; ++k) {
        const fx4* p = (const fx4*)(views + ((size_t)k * NB + b) * ND + off);
        V[k][0] = p[0];
        V[k][1] = p[64];  // +256 floats
    }

    // Phase 2: 30 unique per-lane partial dots.
    float ee[10];  // even-even Gram upper triangle incl. diagonal
    {
        int t = 0;
#pragma unroll
        for (int a = 0; a < 4; ++a)
#pragma unroll
            for (int a2 = a; a2 < 4; ++a2)
                ee[t++] = dot8(V[2*a][0], V[2*a][1], V[2*a2][0], V[2*a2][1]);
    }
    float eo[4][4], oo[4];
#pragma unroll
    for (int j = 0; j < 4; ++j) {
        oo[j] = dot8(V[2*j+1][0], V[2*j+1][1], V[2*j+1][0], V[2*j+1][1]);
#pragma unroll
        for (int a = 0; a < 4; ++a)
            eo[a][j] = dot8(V[2*a][0], V[2*a][1], V[2*j+1][0], V[2*j+1][1]);
    }

    // Phase 3: DPP-reduce all 30 partials; totals land in lane 63.
#pragma unroll
    for (int i = 0; i < 10; ++i) ee[i] = wave_sum63(ee[i]);
#pragma unroll
    for (int a = 0; a < 4; ++a)
#pragma unroll
        for (int j = 0; j < 4; ++j) eo[a][j] = wave_sum63(eo[a][j]);
#pragma unroll
    for (int j = 0; j < 4; ++j) oo[j] = wave_sum63(oo[j]);

    // Phase 4: lane 63 computes the 4 anchor losses and stores the partial.
    if (lane == 63) {
        const int EE[4][4] = {{0,1,2,3},{1,4,5,6},{2,5,7,8},{3,6,8,9}};
        float rn[8];
#pragma unroll
        for (int a = 0; a < 4; ++a) {
            rn[2*a]     = 1.0f / fmaxf(sqrtf(ee[EE[a][a]]), 1e-12f);
            rn[2*a + 1] = 1.0f / fmaxf(sqrtf(oo[a]), 1e-12f);
        }
        float loss = 0.0f;
#pragma unroll
        for (int a = 0; a < 4; ++a) {
            const float ia = rn[2*a];
            const float l0 = T_INV * eo[a][a] * ia * rn[2*a + 1];  // sim_pos
            float lv[6];
            int c = 0;
            float mx = l0;
#pragma unroll
            for (int k = 0; k < 8; ++k) {
                if ((k >> 1) != a) {
                    float s = (k & 1) ? (eo[a][k >> 1] * ia * rn[k])
                                      : (ee[EE[a][k >> 1]] * ia * rn[k]);
                    lv[c] = T_INV * s;
                    mx = fmaxf(mx, lv[c]);
                    ++c;
                }
            }
            float se = __expf(l0 - mx);
#pragma unroll
            for (int i = 0; i < 6; ++i) se += __expf(lv[i] - mx);
            loss += mx + __logf(se) - l0;
        }
        partial[b] = loss;
    }
}

__global__ __launch_bounds__(1024) void ntxent_reduce(const float* __restrict__ partial,
                                                      float* __restrict__ out) {
    __shared__ double sm[1024];
    double s = 0.0;
    for (int i = threadIdx.x; i < NPART; i += 1024) s += (double)partial[i];
    sm[threadIdx.x] = s;
    __syncthreads();
    for (int off = 512; off > 0; off >>= 1) {
        if (threadIdx.x < off) sm[threadIdx.x] += sm[threadIdx.x + off];
        __syncthreads();
    }
    if (threadIdx.x == 0) out[0] = (float)(sm[0] / (double)(NS * NB));
}

extern "C" void kernel_launch(void* const* d_in, const int* in_sizes, int n_in,
                              void* d_out, int out_size, void* d_ws, size_t ws_size,
                              hipStream_t stream) {
    const float* views = (const float*)d_in[0];
    float* out = (float*)d_out;
    float* partial = (float*)d_ws;  // NPART floats = 32 KiB of d_ws

    ntxent_main<<<NBLOCKS, 256, 0, stream>>>(views, partial);
    ntxent_reduce<<<1, 1024, 0, stream>>>(partial, out);
}

// Round 6
// 184.577 us; speedup vs baseline: 1.0610x; 1.0610x over previous
//
#include <hip/hip_runtime.h>
#include <hip/hip_bf16.h>
#include <math.h>

// Problem: IntraSampleNTXEntLoss  S=4, V=2, B=8192, D=512, T=0.1
// views: (S,V,B,D) fp32, flat index ((s*V+v)*B + b)*D + d
// Output: scalar mean loss.
//
// R5 = best-measured config (R3). nt loads kept: the harness's 512 MiB d_ws
// poison fill sweeps L3 between the d_in restore and our launch, so input
// reads are HBM-served either way; nt avoids polluting L2/L3 with a
// never-reused 134 MiB stream. One wave per b; all 16 global_load_dwordx4
// issued up front (max MLP); 30 unique dots (even-even Gram symmetric: 10,
// even-odd: 16, odd self: 4); DPP-only wave reduction (pure VALU, no LDS
// pipe); lane 63 computes the 4 anchor losses (7 finite logits each; masked
// -inf never materialized) and stores one partial per wave. Deterministic
// 1024-thread single-block reduce.
//
// Roofline: main kernel reads 134 MB once, perfectly coalesced (16 B/lane),
// floor = 134 MB / 6.3 TB/s ~= 21 us. Measured window (~190 us) is dominated
// by harness reset traffic: 512 MiB d_ws fill (~79 us @ 6.8 TB/s, top-5) +
// 134 MiB d_in restore (~42 us) + launch gaps. Kernel-side is at the
// HBM-bound roofline.

#define NS 4
#define NB 8192
#define ND 512
#define T_INV 10.0f
#define WAVES_PER_BLOCK 4
#define NBLOCKS (NB / WAVES_PER_BLOCK)
#define NPART NB  // one partial per wave (= per batch element)

typedef float fx4 __attribute__((ext_vector_type(4)));

__device__ __forceinline__ float dot8(const fx4& a0, const fx4& a1,
                                      const fx4& b0, const fx4& b1) {
    return a0.x*b0.x + a0.y*b0.y + a0.z*b0.z + a0.w*b0.w +
           a1.x*b1.x + a1.y*b1.y + a1.z*b1.z + a1.w*b1.w;
}

template <int CTRL, int RM>
__device__ __forceinline__ float dpp_add(float v, float x) {
    int xi = __builtin_bit_cast(int, x);
    int ri = __builtin_amdgcn_update_dpp(0, xi, CTRL, RM, 0xf, true);
    return v + __builtin_bit_cast(float, ri);
}

// Full 64-lane sum; result valid in lane 63. All DPP (VALU pipe only).
__device__ __forceinline__ float wave_sum63(float v) {
    v = dpp_add<0x111, 0xf>(v, v);  // row_shr:1
    v = dpp_add<0x112, 0xf>(v, v);  // row_shr:2
    v = dpp_add<0x114, 0xf>(v, v);  // row_shr:4
    v = dpp_add<0x118, 0xf>(v, v);  // row_shr:8  -> lane 15 of each row16
    v = dpp_add<0x142, 0xa>(v, v);  // row_bcast:15 into rows 1,3
    v = dpp_add<0x143, 0xc>(v, v);  // row_bcast:31 into rows 2,3 -> lane 63
    return v;
}

__global__ __launch_bounds__(256) void ntxent_main(const float* __restrict__ views,
                                                   float* __restrict__ partial) {
    const int wave = threadIdx.x >> 6;
    const int lane = threadIdx.x & 63;
    const int b = blockIdx.x * WAVES_PER_BLOCK + wave;
    const int off = 4 * lane;  // first float4; second at +256 floats

    // Phase 1: issue ALL 16 loads (8 rows x 2 float4); 16 in flight.
    fx4 V[8][2];
#pragma unroll
    for (int k = 0; k < 8; ++k) {
        const fx4* p = (const fx4*)(views + ((size_t)k * NB + b) * ND + off);
        V[k][0] = __builtin_nontemporal_load(p);
        V[k][1] = __builtin_nontemporal_load(p + 64);  // +256 floats
    }

    // Phase 2: 30 unique per-lane partial dots.
    float ee[10];  // even-even Gram upper triangle incl. diagonal
    {
        int t = 0;
#pragma unroll
        for (int a = 0; a < 4; ++a)
#pragma unroll
            for (int a2 = a; a2 < 4; ++a2)
                ee[t++] = dot8(V[2*a][0], V[2*a][1], V[2*a2][0], V[2*a2][1]);
    }
    float eo[4][4], oo[4];
#pragma unroll
    for (int j = 0; j < 4; ++j) {
        oo[j] = dot8(V[2*j+1][0], V[2*j+1][1], V[2*j+1][0], V[2*j+1][1]);
#pragma unroll
        for (int a = 0; a < 4; ++a)
            eo[a][j] = dot8(V[2*a][0], V[2*a][1], V[2*j+1][0], V[2*j+1][1]);
    }

    // Phase 3: DPP-reduce all 30 partials; totals land in lane 63.
#pragma unroll
    for (int i = 0; i < 10; ++i) ee[i] = wave_sum63(ee[i]);
#pragma unroll
    for (int a = 0; a < 4; ++a)
#pragma unroll
        for (int j = 0; j < 4; ++j) eo[a][j] = wave_sum63(eo[a][j]);
#pragma unroll
    for (int j = 0; j < 4; ++j) oo[j] = wave_sum63(oo[j]);

    // Phase 4: lane 63 computes the 4 anchor losses and stores the partial.
    if (lane == 63) {
        const int EE[4][4] = {{0,1,2,3},{1,4,5,6},{2,5,7,8},{3,6,8,9}};
        float rn[8];
#pragma unroll
        for (int a = 0; a < 4; ++a) {
            rn[2*a]     = 1.0f / fmaxf(sqrtf(ee[EE[a][a]]), 1e-12f);
            rn[2*a + 1] = 1.0f / fmaxf(sqrtf(oo[a]), 1e-12f);
        }
        float loss = 0.0f;
#pragma unroll
        for (int a = 0; a < 4; ++a) {
            const float ia = rn[2*a];
            const float l0 = T_INV * eo[a][a] * ia * rn[2*a + 1];  // sim_pos
            float lv[6];
            int c = 0;
            float mx = l0;
#pragma unroll
            for (int k = 0; k < 8; ++k) {
                if ((k >> 1) != a) {
                    float s = (k & 1) ? (eo[a][k >> 1] * ia * rn[k])
                                      : (ee[EE[a][k >> 1]] * ia * rn[k]);
                    lv[c] = T_INV * s;
                    mx = fmaxf(mx, lv[c]);
                    ++c;
                }
            }
            float se = __expf(l0 - mx);
#pragma unroll
            for (int i = 0; i < 6; ++i) se += __expf(lv[i] - mx);
            loss += mx + __logf(se) - l0;
        }
        partial[b] = loss;
    }
}

__global__ __launch_bounds__(1024) void ntxent_reduce(const float* __restrict__ partial,
                                                      float* __restrict__ out) {
    __shared__ double sm[1024];
    double s = 0.0;
    for (int i = threadIdx.x; i < NPART; i += 1024) s += (double)partial[i];
    sm[threadIdx.x] = s;
    __syncthreads();
    for (int off = 512; off > 0; off >>= 1) {
        if (threadIdx.x < off) sm[threadIdx.x] += sm[threadIdx.x + off];
        __syncthreads();
    }
    if (threadIdx.x == 0) out[0] = (float)(sm[0] / (double)(NS * NB));
}

extern "C" void kernel_launch(void* const* d_in, const int* in_sizes, int n_in,
                              void* d_out, int out_size, void* d_ws, size_t ws_size,
                              hipStream_t stream) {
    const float* views = (const float*)d_in[0];
    float* out = (float*)d_out;
    float* partial = (float*)d_ws;  // NPART floats = 32 KiB of d_ws

    ntxent_main<<<NBLOCKS, 256, 0, stream>>>(views, partial);
    ntxent_reduce<<<1, 1024, 0, stream>>>(partial, out);
}